// Round 7
// baseline (507.815 us; speedup 1.0000x reference)
//
#include <hip/hip_runtime.h>
#include <hip/hip_fp16.h>

#define BB 2
#define DX 160
#define DY 160
#define DZ 160

constexpr int    VOL        = DX * DY * DZ;          // 4,096,000
constexpr int    NVOX       = BB * VOL;              // 8,192,000
constexpr size_t PACK_BYTES = (size_t)NVOX * 16;     // 131,072,000 B
constexpr int    ROT        = NVOX / 4;              // 2,048,000 cell rotation

typedef float f2v __attribute__((ext_vector_type(2)));

// ---------------------------------------------------------------------------
// Pack (round-2 per-cell body, PROBE v2: 4 reps with ROTATED cell index).
// Rep r processes cell' = (tid + r*ROT) mod NVOX -- a bijection per rep, so
// each rep is a complete, identically-structured pack pass over DIFFERENT
// addresses in stream order (~33 MB apart). L2 (4 MiB/XCD) cannot carry
// reuse between reps, unlike the r6 probe whose rep 2 was cache-hot.
// => probe duration ~= 4 * P_mem, surfacing pack in the rocprof top-5
// (cutoff ~184 us) for any P > ~46 us, WITH its own FETCH/WRITE counters.
// Races: distinct threads may write the same cell in different reps, but
// always with identical bytes (value depends only on cell and read-only im).
// ---------------------------------------------------------------------------
__global__ __launch_bounds__(256) void pack_kernel(const float* __restrict__ im,
                                                   float4* __restrict__ pk)
{
    const int tid0 = blockIdx.x * blockDim.x + threadIdx.x;
    if (tid0 >= NVOX) return;

    const float2* __restrict__ imf = (const float2*)im;

#pragma unroll 1
    for (int rep = 0; rep < 4; ++rep) {
        int cell = tid0 + rep * ROT;
        if (cell >= NVOX) cell -= NVOX;

        int z = cell % DZ;
        int t = cell / DZ;
        int y = t % DY;
        t /= DY;
        int x = t % DX;
        int b = t / DX;

        const int x1 = min(x + 1, DX - 1);
        const int y1 = min(y + 1, DY - 1);

        const float2 v00 = imf[((b * DX + x ) * DY + y ) * DZ + z];
        const float2 v01 = imf[((b * DX + x ) * DY + y1) * DZ + z];
        const float2 v10 = imf[((b * DX + x1) * DY + y ) * DZ + z];
        const float2 v11 = imf[((b * DX + x1) * DY + y1) * DZ + z];

        __half2 h[4];
        h[0] = __floats2half2_rn(v00.x, v00.y);  // corner (0,0)
        h[1] = __floats2half2_rn(v01.x, v01.y);  // (0,1)
        h[2] = __floats2half2_rn(v10.x, v10.y);  // (1,0)
        h[3] = __floats2half2_rn(v11.x, v11.y);  // (1,1)

        pk[cell] = *(const float4*)h;
    }
}

// ---------------------------------------------------------------------------
// Gather (round-2 version EXACT — best measured): two adjacent 16B quad reads
// per voxel, trilinear in fp32, 4 voxels/thread; defgrid/out non-temporal.
// Same-run container-speed calibration for the pack probe.
// ---------------------------------------------------------------------------
__device__ __forceinline__ void lerp_quads(const float4 Q0, const float4 Q1,
                                           float fx, float fy, float fz,
                                           float& rx, float& ry)
{
    union { float4 f4; __half2 h2[4]; } a, b;
    a.f4 = Q0;
    b.f4 = Q1;

    const float wx[2] = { 1.0f - fx, fx };
    const float wy[2] = { 1.0f - fy, fy };

    rx = 0.0f; ry = 0.0f;
#pragma unroll
    for (int c = 0; c < 4; ++c) {
        const float w = wx[(c >> 1) & 1] * wy[c & 1];
        const float2 v0 = __half22float2(a.h2[c]);
        const float2 v1 = __half22float2(b.h2[c]);
        rx += w * (v0.x + fz * (v1.x - v0.x));
        ry += w * (v0.y + fz * (v1.y - v0.y));
    }
}

__global__ __launch_bounds__(256) void gather_kernel(const float4* __restrict__ pk,
                                                     const float* __restrict__ defgrid,
                                                     float2* __restrict__ out)
{
    constexpr int Q = NVOX / 4;  // 2,048,000
    const int t = blockIdx.x * blockDim.x + threadIdx.x;
    if (t >= Q) return;

    int   idx[4];
    float xf[4], yf[4], zf[4];
#pragma unroll
    for (int k = 0; k < 4; ++k) {
        idx[k] = t + k * Q;
        const float* g = defgrid + (size_t)idx[k] * 3;
        xf[k] = __builtin_nontemporal_load(g + 0);
        yf[k] = __builtin_nontemporal_load(g + 1);
        zf[k] = __builtin_nontemporal_load(g + 2);
    }

    size_t q0[4], q1[4];
    float  fx[4], fy[4], fz[4];
#pragma unroll
    for (int k = 0; k < 4; ++k) {
        const int ax = min(max((int)floorf(xf[k]), 0), DX - 1);
        const int ay = min(max((int)floorf(yf[k]), 0), DY - 1);
        const int az = min(max((int)floorf(zf[k]), 0), DZ - 1);
        const int z1 = min(az + 1, DZ - 1);
        const int b  = (idx[k] >= VOL) ? 1 : 0;
        const size_t base = (size_t)(((b * DX + ax) * DY + ay)) * DZ;
        q0[k] = base + az;
        q1[k] = base + z1;
        fx[k] = xf[k] - (float)ax;
        fy[k] = yf[k] - (float)ay;
        fz[k] = zf[k] - (float)az;
    }

    // issue all 8 quad loads before consuming
    float4 A[4], B[4];
#pragma unroll
    for (int k = 0; k < 4; ++k) {
        A[k] = pk[q0[k]];
        B[k] = pk[q1[k]];
    }

#pragma unroll
    for (int k = 0; k < 4; ++k) {
        float rx, ry;
        lerp_quads(A[k], B[k], fx[k], fy[k], fz[k], rx, ry);
        f2v r;
        r.x = rx;
        r.y = ry;
        __builtin_nontemporal_store(r, (f2v*)(out + idx[k]));
    }
}

// ---------------------------------------------------------------------------
// Fallback direct kernel in case ws_size < PACK_BYTES.
// ---------------------------------------------------------------------------
__global__ __launch_bounds__(256) void trilerp3d_direct(
    const float* __restrict__ im,
    const float* __restrict__ defgrid,
    float*       __restrict__ out)
{
    int idx = blockIdx.x * blockDim.x + threadIdx.x;
    if (idx >= NVOX) return;

    const float x = defgrid[(size_t)idx * 3 + 0];
    const float y = defgrid[(size_t)idx * 3 + 1];
    const float z = defgrid[(size_t)idx * 3 + 2];

    const int x0u = (int)floorf(x);
    const int y0u = (int)floorf(y);
    const int z0u = (int)floorf(z);

    const int x0 = min(max(x0u, 0), DX - 1);
    const int x1 = min(max(x0u + 1, 0), DX - 1);
    const int y0 = min(max(y0u, 0), DY - 1);
    const int y1 = min(max(y0u + 1, 0), DY - 1);
    const int z0 = min(max(z0u, 0), DZ - 1);
    const int z1 = min(max(z0u + 1, 0), DZ - 1);

    const float xd = x - (float)x0;
    const float yd = y - (float)y0;
    const float zd = z - (float)z0;

    const int b    = idx / VOL;
    const int base = b * VOL;

    const float2* __restrict__ imf = (const float2*)im;

    const int px0 = base + x0 * (DY * DZ);
    const int px1 = base + x1 * (DY * DZ);
    const int oy0 = y0 * DZ;
    const int oy1 = y1 * DZ;

    const float2 Ia = imf[px0 + oy0 + z0];
    const float2 Ib = imf[px0 + oy0 + z1];
    const float2 Ic = imf[px0 + oy1 + z0];
    const float2 Id = imf[px0 + oy1 + z1];
    const float2 Ie = imf[px1 + oy0 + z0];
    const float2 If = imf[px1 + oy0 + z1];
    const float2 Ig = imf[px1 + oy1 + z0];
    const float2 Ih = imf[px1 + oy1 + z1];

    const float xm = 1.0f - xd, ym = 1.0f - yd, zm = 1.0f - zd;

    float cae_x = Ia.x * xm + Ie.x * xd;
    float cae_y = Ia.y * xm + Ie.y * xd;
    float cbf_x = Ib.x * xm + If.x * xd;
    float cbf_y = Ib.y * xm + If.y * xd;
    float ccg_x = Ic.x * xm + Ig.x * xd;
    float ccg_y = Ic.y * xm + Ig.y * xd;
    float cdh_x = Id.x * xm + Ih.x * xd;
    float cdh_y = Id.y * xm + Ih.y * xd;

    float c0_x = cae_x * ym + ccg_x * yd;
    float c0_y = cae_y * ym + ccg_y * yd;
    float c1_x = cbf_x * ym + cdh_x * yd;
    float c1_y = cbf_y * ym + cdh_y * yd;

    float2 r;
    r.x = c0_x * zm + c1_x * zd;
    r.y = c0_y * zm + c1_y * zd;
    ((float2*)out)[idx] = r;
}

extern "C" void kernel_launch(void* const* d_in, const int* in_sizes, int n_in,
                              void* d_out, int out_size, void* d_ws, size_t ws_size,
                              hipStream_t stream) {
    const float* im      = (const float*)d_in[0];
    const float* defgrid = (const float*)d_in[1];
    float*       out     = (float*)d_out;

    const int block = 256;

    if (ws_size >= PACK_BYTES) {
        float4* pk = (float4*)d_ws;
        const int gridP = (NVOX + block - 1) / block;      // 32000
        pack_kernel<<<gridP, block, 0, stream>>>(im, pk);
        const int gridG = (NVOX / 4 + block - 1) / block;  // 8000
        gather_kernel<<<gridG, block, 0, stream>>>(pk, defgrid, (float2*)out);
    } else {
        const int grid = (NVOX + block - 1) / block;
        trilerp3d_direct<<<grid, block, 0, stream>>>(im, defgrid, out);
    }
}

// Round 8
// 367.781 us; speedup vs baseline: 1.3808x; 1.3808x over previous
//
#include <hip/hip_runtime.h>
#include <hip/hip_fp16.h>

#define BB 2
#define DX 160
#define DY 160
#define DZ 160

constexpr int    VOL        = DX * DY * DZ;          // 4,096,000
constexpr int    NVOX       = BB * VOL;              // 8,192,000
constexpr size_t PACK_BYTES = (size_t)NVOX * 16;     // 131,072,000 B

typedef float f2v __attribute__((ext_vector_type(2)));

// ---------------------------------------------------------------------------
// FINAL (= round-2 configuration, best verified 367.8 us).
// Measured budget (r7 rotated-rep probe): pack ~48 us (231 MB @ 4.8 TB/s,
// ~77% of stream ceiling, read amp only 1.58x), gather ~184 us (605 MB fetch
// of which ~500 MB random 64B lines @ ~3.6 TB/s -- invariant across three
// structurally different layouts/MLP depths => hardware random-line ceiling),
// ~135 us harness reset overhead (dispatch-ID spacing ~66/iter).
//
// Pack: per (b,x,y,z) store the XY-QUAD at that z: corners (x,y),(x,y+1),
// (x+1,y),(x+1,y+1) clamped, 2ch fp16 = 16 B = one float4, contiguous in z.
// A sample reads quad(z) and quad(z+1): adjacent 16B slots, 1.25 lines avg.
// ---------------------------------------------------------------------------
__global__ __launch_bounds__(256) void pack_kernel(const float* __restrict__ im,
                                                   float4* __restrict__ pk)
{
    int cell = blockIdx.x * blockDim.x + threadIdx.x;
    if (cell >= NVOX) return;

    int z = cell % DZ;
    int t = cell / DZ;
    int y = t % DY;
    t /= DY;
    int x = t % DX;
    int b = t / DX;

    const float2* __restrict__ imf = (const float2*)im;

    const int x1 = min(x + 1, DX - 1);
    const int y1 = min(y + 1, DY - 1);

    const float2 v00 = imf[((b * DX + x ) * DY + y ) * DZ + z];
    const float2 v01 = imf[((b * DX + x ) * DY + y1) * DZ + z];
    const float2 v10 = imf[((b * DX + x1) * DY + y ) * DZ + z];
    const float2 v11 = imf[((b * DX + x1) * DY + y1) * DZ + z];

    __half2 h[4];
    h[0] = __floats2half2_rn(v00.x, v00.y);  // corner (0,0)
    h[1] = __floats2half2_rn(v01.x, v01.y);  // (0,1)
    h[2] = __floats2half2_rn(v10.x, v10.y);  // (1,0)
    h[3] = __floats2half2_rn(v11.x, v11.y);  // (1,1)

    pk[cell] = *(const float4*)h;            // cached store
}

// ---------------------------------------------------------------------------
// Gather: two adjacent 16B quad reads per voxel, trilinear in fp32,
// 4 voxels/thread; defgrid/out non-temporal streams.
// ---------------------------------------------------------------------------
__device__ __forceinline__ void lerp_quads(const float4 Q0, const float4 Q1,
                                           float fx, float fy, float fz,
                                           float& rx, float& ry)
{
    union { float4 f4; __half2 h2[4]; } a, b;
    a.f4 = Q0;
    b.f4 = Q1;

    const float wx[2] = { 1.0f - fx, fx };
    const float wy[2] = { 1.0f - fy, fy };

    rx = 0.0f; ry = 0.0f;
#pragma unroll
    for (int c = 0; c < 4; ++c) {
        const float w = wx[(c >> 1) & 1] * wy[c & 1];
        const float2 v0 = __half22float2(a.h2[c]);
        const float2 v1 = __half22float2(b.h2[c]);
        rx += w * (v0.x + fz * (v1.x - v0.x));
        ry += w * (v0.y + fz * (v1.y - v0.y));
    }
}

__global__ __launch_bounds__(256) void gather_kernel(const float4* __restrict__ pk,
                                                     const float* __restrict__ defgrid,
                                                     float2* __restrict__ out)
{
    constexpr int Q = NVOX / 4;  // 2,048,000
    const int t = blockIdx.x * blockDim.x + threadIdx.x;
    if (t >= Q) return;

    int   idx[4];
    float xf[4], yf[4], zf[4];
#pragma unroll
    for (int k = 0; k < 4; ++k) {
        idx[k] = t + k * Q;
        const float* g = defgrid + (size_t)idx[k] * 3;
        xf[k] = __builtin_nontemporal_load(g + 0);
        yf[k] = __builtin_nontemporal_load(g + 1);
        zf[k] = __builtin_nontemporal_load(g + 2);
    }

    size_t q0[4], q1[4];
    float  fx[4], fy[4], fz[4];
#pragma unroll
    for (int k = 0; k < 4; ++k) {
        const int ax = min(max((int)floorf(xf[k]), 0), DX - 1);
        const int ay = min(max((int)floorf(yf[k]), 0), DY - 1);
        const int az = min(max((int)floorf(zf[k]), 0), DZ - 1);
        const int z1 = min(az + 1, DZ - 1);
        const int b  = (idx[k] >= VOL) ? 1 : 0;
        const size_t base = (size_t)(((b * DX + ax) * DY + ay)) * DZ;
        q0[k] = base + az;
        q1[k] = base + z1;
        fx[k] = xf[k] - (float)ax;
        fy[k] = yf[k] - (float)ay;
        fz[k] = zf[k] - (float)az;
    }

    // issue all 8 quad loads before consuming
    float4 A[4], B[4];
#pragma unroll
    for (int k = 0; k < 4; ++k) {
        A[k] = pk[q0[k]];
        B[k] = pk[q1[k]];
    }

#pragma unroll
    for (int k = 0; k < 4; ++k) {
        float rx, ry;
        lerp_quads(A[k], B[k], fx[k], fy[k], fz[k], rx, ry);
        f2v r;
        r.x = rx;
        r.y = ry;
        __builtin_nontemporal_store(r, (f2v*)(out + idx[k]));
    }
}

// ---------------------------------------------------------------------------
// Fallback direct kernel in case ws_size < PACK_BYTES.
// ---------------------------------------------------------------------------
__global__ __launch_bounds__(256) void trilerp3d_direct(
    const float* __restrict__ im,
    const float* __restrict__ defgrid,
    float*       __restrict__ out)
{
    int idx = blockIdx.x * blockDim.x + threadIdx.x;
    if (idx >= NVOX) return;

    const float x = defgrid[(size_t)idx * 3 + 0];
    const float y = defgrid[(size_t)idx * 3 + 1];
    const float z = defgrid[(size_t)idx * 3 + 2];

    const int x0u = (int)floorf(x);
    const int y0u = (int)floorf(y);
    const int z0u = (int)floorf(z);

    const int x0 = min(max(x0u, 0), DX - 1);
    const int x1 = min(max(x0u + 1, 0), DX - 1);
    const int y0 = min(max(y0u, 0), DY - 1);
    const int y1 = min(max(y0u + 1, 0), DY - 1);
    const int z0 = min(max(z0u, 0), DZ - 1);
    const int z1 = min(max(z0u + 1, 0), DZ - 1);

    const float xd = x - (float)x0;
    const float yd = y - (float)y0;
    const float zd = z - (float)z0;

    const int b    = idx / VOL;
    const int base = b * VOL;

    const float2* __restrict__ imf = (const float2*)im;

    const int px0 = base + x0 * (DY * DZ);
    const int px1 = base + x1 * (DY * DZ);
    const int oy0 = y0 * DZ;
    const int oy1 = y1 * DZ;

    const float2 Ia = imf[px0 + oy0 + z0];
    const float2 Ib = imf[px0 + oy0 + z1];
    const float2 Ic = imf[px0 + oy1 + z0];
    const float2 Id = imf[px0 + oy1 + z1];
    const float2 Ie = imf[px1 + oy0 + z0];
    const float2 If = imf[px1 + oy0 + z1];
    const float2 Ig = imf[px1 + oy1 + z0];
    const float2 Ih = imf[px1 + oy1 + z1];

    const float xm = 1.0f - xd, ym = 1.0f - yd, zm = 1.0f - zd;

    float cae_x = Ia.x * xm + Ie.x * xd;
    float cae_y = Ia.y * xm + Ie.y * xd;
    float cbf_x = Ib.x * xm + If.x * xd;
    float cbf_y = Ib.y * xm + If.y * xd;
    float ccg_x = Ic.x * xm + Ig.x * xd;
    float ccg_y = Ic.y * xm + Ig.y * xd;
    float cdh_x = Id.x * xm + Ih.x * xd;
    float cdh_y = Id.y * xm + Ih.y * xd;

    float c0_x = cae_x * ym + ccg_x * yd;
    float c0_y = cae_y * ym + ccg_y * yd;
    float c1_x = cbf_x * ym + cdh_x * yd;
    float c1_y = cbf_y * ym + cdh_y * yd;

    float2 r;
    r.x = c0_x * zm + c1_x * zd;
    r.y = c0_y * zm + c1_y * zd;
    ((float2*)out)[idx] = r;
}

extern "C" void kernel_launch(void* const* d_in, const int* in_sizes, int n_in,
                              void* d_out, int out_size, void* d_ws, size_t ws_size,
                              hipStream_t stream) {
    const float* im      = (const float*)d_in[0];
    const float* defgrid = (const float*)d_in[1];
    float*       out     = (float*)d_out;

    const int block = 256;

    if (ws_size >= PACK_BYTES) {
        float4* pk = (float4*)d_ws;
        const int gridP = (NVOX + block - 1) / block;      // 32000
        pack_kernel<<<gridP, block, 0, stream>>>(im, pk);
        const int gridG = (NVOX / 4 + block - 1) / block;  // 8000
        gather_kernel<<<gridG, block, 0, stream>>>(pk, defgrid, (float2*)out);
    } else {
        const int grid = (NVOX + block - 1) / block;
        trilerp3d_direct<<<grid, block, 0, stream>>>(im, defgrid, out);
    }
}